// Round 8
// baseline (2427.705 us; speedup 1.0000x reference)
//
#include <hip/hip_runtime.h>
#include <hip/hip_bf16.h>

#define BB 512
#define VV 6890
#define NJ 24
#define NBETA 10
#define NP 207          // (24-1)*9
#define N3 (VV*3)       // 20670
#define TBAT 8          // batch tile in k_fused
#define NCH 16          // v-chunks in k_jreg
#define CHV ((VV + NCH - 1) / NCH)   // 431

// d_out element offsets (fp32), concatenated in return order:
// verts (B,V,3), posed_joints (B,J,3), A (B,J,4,4), transforms (B,J,4,4), v_posed (B,V,3)
#define OFF_VERTS 0
#define OFF_PJ   (BB*VV*3)
#define OFF_A    (OFF_PJ + BB*NJ*3)
#define OFF_TF   (OFF_A + BB*NJ*16)
#define OFF_VP   (OFF_TF + BB*NJ*16)

// ws layout (fp32 elements)
#define WS_JP   0                        // NCH*24*33 partials of [JT[3]|JS[30]]
#define WS_PF   (WS_JP + NCH*NJ*33)      // B*207 pose_feature
#define WS_A    (WS_PF + BB*NP)          // B*24*16 fp32 A

// SMPL parents are a compile-time constant in the reference — hardcoded.
__constant__ int c_par[NJ] = {-1, 0, 0, 0, 1, 2, 3, 4, 5, 6, 7, 8,
                              9, 9, 9, 12, 13, 14, 16, 17, 18, 19, 20, 21};

// ------------------------------------------------- K1: partial JT/JS sums
__global__ __launch_bounds__(256) void k_jreg(const float* __restrict__ jr,
                                              const float* __restrict__ vt,
                                              const float* __restrict__ sd,
                                              float* __restrict__ ws_jp) {
    int j = blockIdx.x, ch = blockIdx.y;
    int t = threadIdx.x;
    int v0 = ch * CHV;
    int vend = (v0 + CHV < VV) ? (v0 + CHV) : VV;

    float acc[33];
#pragma unroll
    for (int i = 0; i < 33; i++) acc[i] = 0.f;

    for (int v = v0 + t; v < vend; v += 256) {
        float a = jr[(size_t)j * VV + v];
        acc[0] += a * vt[v * 3 + 0];
        acc[1] += a * vt[v * 3 + 1];
        acc[2] += a * vt[v * 3 + 2];
        const float2* sp = (const float2*)&sd[(size_t)v * 30];   // 8B-aligned
#pragma unroll
        for (int i = 0; i < 15; i++) {
            float2 s = sp[i];
            acc[3 + 2 * i] += a * s.x;
            acc[4 + 2 * i] += a * s.y;
        }
    }

    __shared__ float red[33][256];
#pragma unroll
    for (int i = 0; i < 33; i++) red[i][t] = acc[i];
    __syncthreads();
    for (int s = 128; s > 0; s >>= 1) {
        if (t < s) {
#pragma unroll
            for (int i = 0; i < 33; i++) red[i][t] += red[i][t + s];
        }
        __syncthreads();
    }
    if (t < 33) ws_jp[(size_t)(ch * NJ + j) * 33 + t] = red[t][0];
}

// ------------------------------- K2: Jloc, Rodrigues, chain, A/transforms/joints
__global__ __launch_bounds__(64) void k_chain(
        const float* __restrict__ betas,
        const float* __restrict__ pose,
        const float* __restrict__ ws_jp,
        float* __restrict__ ws_pf,
        float* __restrict__ ws_A,
        float* __restrict__ out) {
    int b = blockIdx.x;
    int t = threadIdx.x;
    __shared__ float Jl[NJ][3];
    __shared__ float tm[NJ][16];
    __shared__ float ch[NJ][16];
    float R[9];

    if (t < NJ) {
        int j = t;
        float s[33];
#pragma unroll
        for (int i = 0; i < 33; i++) s[i] = 0.f;
        for (int c = 0; c < NCH; c++) {
            const float* pp = ws_jp + (size_t)(c * NJ + j) * 33;
#pragma unroll
            for (int i = 0; i < 33; i++) s[i] += pp[i];
        }
        float bb[NBETA];
#pragma unroll
        for (int l = 0; l < NBETA; l++) bb[l] = betas[b * NBETA + l];
#pragma unroll
        for (int k = 0; k < 3; k++) {
            float acc = s[k];
#pragma unroll
            for (int l = 0; l < NBETA; l++) acc += bb[l] * s[3 + k * NBETA + l];
            Jl[j][k] = acc;
        }
        // Rodrigues, matching reference: angle = ||aa + 1e-8||, rd = aa/angle
        float ax = pose[b * NJ * 3 + j * 3 + 0];
        float ay = pose[b * NJ * 3 + j * 3 + 1];
        float az = pose[b * NJ * 3 + j * 3 + 2];
        float e0 = ax + 1e-8f, e1 = ay + 1e-8f, e2 = az + 1e-8f;
        float ang = sqrtf(e0 * e0 + e1 * e1 + e2 * e2);
        float inv = 1.f / ang;
        float rx = ax * inv, ry = ay * inv, rz = az * inv;
        float sn = sinf(ang), cs = cosf(ang);
        float Km[9] = {0.f, -rz, ry, rz, 0.f, -rx, -ry, rx, 0.f};
#pragma unroll
        for (int r = 0; r < 3; r++)
#pragma unroll
            for (int c = 0; c < 3; c++) {
                float kk = Km[3 * r + 0] * Km[0 + c] + Km[3 * r + 1] * Km[3 + c] +
                           Km[3 * r + 2] * Km[6 + c];
                R[3 * r + c] = ((r == c) ? 1.f : 0.f) + sn * Km[3 * r + c] + (1.f - cs) * kk;
            }
        if (j >= 1) {
#pragma unroll
            for (int e = 0; e < 9; e++) {
                int r = e / 3, c = e % 3;
                ws_pf[b * NP + (j - 1) * 9 + e] = R[e] - ((r == c) ? 1.f : 0.f);
            }
        }
    }
    __syncthreads();
    if (t < NJ) {
        int j = t;
        int p = c_par[j];
        int ps = (p < 0) ? 0 : p;
#pragma unroll
        for (int r = 0; r < 3; r++) {
            tm[j][r * 4 + 0] = R[3 * r + 0];
            tm[j][r * 4 + 1] = R[3 * r + 1];
            tm[j][r * 4 + 2] = R[3 * r + 2];
            tm[j][r * 4 + 3] = (j == 0) ? Jl[j][r] : (Jl[j][r] - Jl[ps][r]);
        }
        tm[j][12] = 0.f; tm[j][13] = 0.f; tm[j][14] = 0.f; tm[j][15] = 1.f;
    }
    __syncthreads();
    if (t < 16) ch[0][t] = tm[0][t];
    __syncthreads();
    for (int i = 1; i < NJ; i++) {
        if (t < 16) {
            int r = t >> 2, c = t & 3;
            int p = c_par[i];
            ch[i][t] = ch[p][4 * r + 0] * tm[i][0 + c] + ch[p][4 * r + 1] * tm[i][4 + c] +
                       ch[p][4 * r + 2] * tm[i][8 + c] + ch[p][4 * r + 3] * tm[i][12 + c];
        }
        __syncthreads();
    }
    if (t < NJ) {
        int j = t;
        float ib[4];
#pragma unroll
        for (int p = 0; p < 4; p++)
            ib[p] = ch[j][4 * p + 0] * Jl[j][0] + ch[j][4 * p + 1] * Jl[j][1] +
                    ch[j][4 * p + 2] * Jl[j][2];
#pragma unroll
        for (int e = 0; e < 16; e++) {
            int r = e >> 2, c = e & 3;
            float tr = ch[j][e];
            float Ae = tr - ((c == 3) ? ib[r] : 0.f);
            out[OFF_TF + (size_t)(b * NJ + j) * 16 + e] = tr;
            out[OFF_A + (size_t)(b * NJ + j) * 16 + e] = Ae;
            ws_A[(size_t)(b * NJ + j) * 16 + e] = Ae;
        }
#pragma unroll
        for (int k = 0; k < 3; k++)
            out[OFF_PJ + (size_t)(b * NJ + j) * 3 + k] = ch[j][4 * k + 3];
    }
}

// ----------- K3 (FUSED): v_posed = vt + sd@betas + pf@posedirs ; verts = (lw@A)·vp
// r7 post-mortem: VGPR=116 -> only 4 waves/SIMD ceiling, measured occupancy 17.6%
// -> latency-bound at VALUBusy 56%. Useful VALU floor is ~46us; the gap is pure
// exposure from too few resident waves. This round: VGPR down, occupancy up.
//   - __launch_bounds__(256, 6): cap VGPR at 85 (live set ~60 -> safe margin
//     from the r6 spill cliff; WRITE_SIZE is the spill canary).
//   - K-chunk 4 (p regs 24->12), 51 clean chunks + 3-row tail (no clamp/pad).
//   - pass B reads lw 4-at-a-time inside the j-loop (no wv[24] preload; lw line
//     is L1-resident after bi=0).
// Broadcast operands (pf, A, betas) stay in LDS (r0-r5: s_load chains pin VALU
// at 40%). XCD swizzle keeps each XCD's pd slice L2-resident (r2-verified).
__global__ __launch_bounds__(256, 6) void k_fused(
        const float* __restrict__ vt,
        const float* __restrict__ sd,
        const float* __restrict__ betas,
        const float* __restrict__ pd,
        const float* __restrict__ ws_pf,
        const float* __restrict__ ws_A,
        const float* __restrict__ lw,
        float* __restrict__ out) {
    int id = blockIdx.x;
    int xcd = id & 7, li = id >> 3;
    int nx = (xcd < 3) ? 4 : 3;                  // 27 x-slices = 3*4 + 5*3
    if (li >= nx * (BB / TBAT)) return;          // whole-block exit (before barriers)
    int x = xcd + 8 * (li % nx);
    int b0 = (li / nx) * TBAT;
    int t = threadIdx.x;
    int v = x * 256 + t;
    bool act = (v < VV);
    int vc = act ? v : (VV - 1);                 // clamp reads; predicate writes
    int n0 = vc * 3;

    __shared__ __align__(16) float pfs[TBAT][208];   // pose_feature rows (207 + 1 align pad)
    __shared__ __align__(16) float As[TBAT][288];    // A[:3][:4] rows, flat 24*12
    __shared__ __align__(16) float bbs[TBAT][NBETA];

    // ---- stage broadcast operands (coalesced, all threads participate)
    for (int idx = t; idx < TBAT * NP; idx += 256) {
        int bi = idx / NP, p = idx - bi * NP;
        pfs[bi][p] = ws_pf[(size_t)(b0 + bi) * NP + p];
    }
    for (int idx = t; idx < TBAT * 288; idx += 256) {
        int bi = idx / 288, r = idx - bi * 288;
        int j = r / 12, e = r - j * 12;
        As[bi][r] = ws_A[(size_t)(b0 + bi) * (NJ * 16) + j * 16 + e];
    }
    if (t < TBAT * NBETA) {
        int bi = t / NBETA, l = t - bi * NBETA;
        bbs[bi][l] = betas[(size_t)(b0 + bi) * NBETA + l];
    }
    __syncthreads();

    float acc0[TBAT], acc1[TBAT], acc2[TBAT];
#pragma unroll
    for (int bi = 0; bi < TBAT; bi++) { acc0[bi] = 0.f; acc1[bi] = 0.f; acc2[bi] = 0.f; }

    const float* __restrict__ pdp = pd + n0;

    // ---- main loop: 51 chunks of 4 rows (rows 0..203), then 3-row tail
#pragma unroll 1
    for (int c0 = 0; c0 < 204; c0 += 4) {
        float p0[4], p1[4], p2[4];
#pragma unroll
        for (int pc = 0; pc < 4; pc++) {
            const float* rp = pdp + (size_t)(c0 + pc) * N3;
            p0[pc] = rp[0]; p1[pc] = rp[1]; p2[pc] = rp[2];   // dwordx3/wave
        }
#pragma unroll
        for (int bi = 0; bi < TBAT; bi++) {
            float2 wa = *(const float2*)&pfs[bi][c0];         // b64 broadcast
            float2 wb = *(const float2*)&pfs[bi][c0 + 2];
            acc0[bi] += wa.x * p0[0]; acc1[bi] += wa.x * p1[0]; acc2[bi] += wa.x * p2[0];
            acc0[bi] += wa.y * p0[1]; acc1[bi] += wa.y * p1[1]; acc2[bi] += wa.y * p2[1];
            acc0[bi] += wb.x * p0[2]; acc1[bi] += wb.x * p1[2]; acc2[bi] += wb.x * p2[2];
            acc0[bi] += wb.y * p0[3]; acc1[bi] += wb.y * p1[3]; acc2[bi] += wb.y * p2[3];
        }
    }
    {   // tail: rows 204..206
        float p0[3], p1[3], p2[3];
#pragma unroll
        for (int pc = 0; pc < 3; pc++) {
            const float* rp = pdp + (size_t)(204 + pc) * N3;
            p0[pc] = rp[0]; p1[pc] = rp[1]; p2[pc] = rp[2];
        }
#pragma unroll
        for (int bi = 0; bi < TBAT; bi++) {
            float w0 = pfs[bi][204], w1 = pfs[bi][205], w2 = pfs[bi][206];
            acc0[bi] += w0 * p0[0]; acc1[bi] += w0 * p1[0]; acc2[bi] += w0 * p2[0];
            acc0[bi] += w1 * p0[1]; acc1[bi] += w1 * p1[1]; acc2[bi] += w1 * p2[1];
            acc0[bi] += w2 * p0[2]; acc1[bi] += w2 * p1[2]; acc2[bi] += w2 * p2[2];
        }
    }

    // ---- pass A: vp = vt + sd@betas + acc ; store vp; acc registers now carry vp
    {
        float vt0 = vt[n0], vt1 = vt[n0 + 1], vt2 = vt[n0 + 2];
        float sdv[3][NBETA];
#pragma unroll
        for (int k = 0; k < 3; k++)
#pragma unroll
            for (int l = 0; l < NBETA; l++)
                sdv[k][l] = sd[(size_t)vc * 30 + k * NBETA + l];
#pragma unroll
        for (int bi = 0; bi < TBAT; bi++) {
            float s0 = vt0 + acc0[bi], s1 = vt1 + acc1[bi], s2 = vt2 + acc2[bi];
#pragma unroll
            for (int l = 0; l < NBETA; l++) {
                float bl = bbs[bi][l];                   // b32 broadcast
                s0 += bl * sdv[0][l];
                s1 += bl * sdv[1][l];
                s2 += bl * sdv[2][l];
            }
            if (act) {
                float* op = &out[OFF_VP + (size_t)(b0 + bi) * N3 + n0];
                op[0] = s0; op[1] = s1; op[2] = s2;
            }
            acc0[bi] = s0; acc1[bi] = s1; acc2[bi] = s2;   // reuse regs (sdv dies here)
        }
    }

    // ---- pass B: T = lw@A (LDS b128 broadcast); verts from in-register vp.
    // lw read 4 weights at a time inside the loop (L1-hot after bi=0) -> low live set.
#pragma unroll
    for (int bi = 0; bi < TBAT; bi++) {
        float T[12];
#pragma unroll
        for (int e = 0; e < 12; e++) T[e] = 0.f;
#pragma unroll
        for (int j0 = 0; j0 < NJ; j0 += 4) {
            const float4 w4 = *(const float4*)&lw[(size_t)vc * NJ + j0];  // 16B-aligned
#pragma unroll
            for (int jj = 0; jj < 4; jj++) {
                int j = j0 + jj;
                float wj = (jj == 0) ? w4.x : (jj == 1) ? w4.y : (jj == 2) ? w4.z : w4.w;
                const float4 a0 = *(const float4*)&As[bi][j * 12 + 0];   // b128 broadcast
                const float4 a1 = *(const float4*)&As[bi][j * 12 + 4];
                const float4 a2 = *(const float4*)&As[bi][j * 12 + 8];
                T[0] += wj * a0.x; T[1] += wj * a0.y; T[2]  += wj * a0.z; T[3]  += wj * a0.w;
                T[4] += wj * a1.x; T[5] += wj * a1.y; T[6]  += wj * a1.z; T[7]  += wj * a1.w;
                T[8] += wj * a2.x; T[9] += wj * a2.y; T[10] += wj * a2.z; T[11] += wj * a2.w;
            }
        }
        if (act) {
            float s0 = acc0[bi], s1 = acc1[bi], s2 = acc2[bi];
            float* op = &out[OFF_VERTS + (size_t)(b0 + bi) * N3 + n0];
            op[0] = T[0] * s0 + T[1] * s1 + T[2]  * s2 + T[3];
            op[1] = T[4] * s0 + T[5] * s1 + T[6]  * s2 + T[7];
            op[2] = T[8] * s0 + T[9] * s1 + T[10] * s2 + T[11];
        }
    }
}

extern "C" void kernel_launch(void* const* d_in, const int* in_sizes, int n_in,
                              void* d_out, int out_size, void* d_ws, size_t ws_size,
                              hipStream_t stream) {
    const float* betas = (const float*)d_in[0];
    const float* pose  = (const float*)d_in[1];
    const float* vt    = (const float*)d_in[2];
    const float* sd    = (const float*)d_in[3];
    const float* pd    = (const float*)d_in[4];
    const float* jr    = (const float*)d_in[5];
    const float* lw    = (const float*)d_in[6];
    float* out = (float*)d_out;
    float* ws = (float*)d_ws;

    k_jreg<<<dim3(NJ, NCH), 256, 0, stream>>>(jr, vt, sd, ws + WS_JP);
    k_chain<<<BB, 64, 0, stream>>>(betas, pose, ws + WS_JP, ws + WS_PF,
                                   ws + WS_A, out);
    // 8 XCDs x max 4 x-slices x 64 batch-groups = 2048 launched, 1728 live
    k_fused<<<8 * 4 * (BB / TBAT), 256, 0, stream>>>(
        vt, sd, betas, pd, ws + WS_PF, ws + WS_A, lw, out);
}

// Round 9
// 441.765 us; speedup vs baseline: 5.4955x; 5.4955x over previous
//
#include <hip/hip_runtime.h>
#include <hip/hip_bf16.h>

#define BB 512
#define VV 6890
#define NJ 24
#define NBETA 10
#define NP 207          // (24-1)*9
#define N3 (VV*3)       // 20670
#define TBAT 8          // batch tile in k_fused
#define NCH 16          // v-chunks in k_jreg
#define CHV ((VV + NCH - 1) / NCH)   // 431

// d_out element offsets (fp32), concatenated in return order:
// verts (B,V,3), posed_joints (B,J,3), A (B,J,4,4), transforms (B,J,4,4), v_posed (B,V,3)
#define OFF_VERTS 0
#define OFF_PJ   (BB*VV*3)
#define OFF_A    (OFF_PJ + BB*NJ*3)
#define OFF_TF   (OFF_A + BB*NJ*16)
#define OFF_VP   (OFF_TF + BB*NJ*16)

// ws layout (fp32 elements)
#define WS_JP   0                        // NCH*24*33 partials of [JT[3]|JS[30]]
#define WS_PF   (WS_JP + NCH*NJ*33)      // B*207 pose_feature
#define WS_A    (WS_PF + BB*NP)          // B*24*16 fp32 A

// SMPL parents are a compile-time constant in the reference — hardcoded.
__constant__ int c_par[NJ] = {-1, 0, 0, 0, 1, 2, 3, 4, 5, 6, 7, 8,
                              9, 9, 9, 12, 13, 14, 16, 17, 18, 19, 20, 21};

// ------------------------------------------------- K1: partial JT/JS sums
__global__ __launch_bounds__(256) void k_jreg(const float* __restrict__ jr,
                                              const float* __restrict__ vt,
                                              const float* __restrict__ sd,
                                              float* __restrict__ ws_jp) {
    int j = blockIdx.x, ch = blockIdx.y;
    int t = threadIdx.x;
    int v0 = ch * CHV;
    int vend = (v0 + CHV < VV) ? (v0 + CHV) : VV;

    float acc[33];
#pragma unroll
    for (int i = 0; i < 33; i++) acc[i] = 0.f;

    for (int v = v0 + t; v < vend; v += 256) {
        float a = jr[(size_t)j * VV + v];
        acc[0] += a * vt[v * 3 + 0];
        acc[1] += a * vt[v * 3 + 1];
        acc[2] += a * vt[v * 3 + 2];
        const float2* sp = (const float2*)&sd[(size_t)v * 30];   // 8B-aligned
#pragma unroll
        for (int i = 0; i < 15; i++) {
            float2 s = sp[i];
            acc[3 + 2 * i] += a * s.x;
            acc[4 + 2 * i] += a * s.y;
        }
    }

    __shared__ float red[33][256];
#pragma unroll
    for (int i = 0; i < 33; i++) red[i][t] = acc[i];
    __syncthreads();
    for (int s = 128; s > 0; s >>= 1) {
        if (t < s) {
#pragma unroll
            for (int i = 0; i < 33; i++) red[i][t] += red[i][t + s];
        }
        __syncthreads();
    }
    if (t < 33) ws_jp[(size_t)(ch * NJ + j) * 33 + t] = red[t][0];
}

// ------------------------------- K2: Jloc, Rodrigues, chain, A/transforms/joints
__global__ __launch_bounds__(64) void k_chain(
        const float* __restrict__ betas,
        const float* __restrict__ pose,
        const float* __restrict__ ws_jp,
        float* __restrict__ ws_pf,
        float* __restrict__ ws_A,
        float* __restrict__ out) {
    int b = blockIdx.x;
    int t = threadIdx.x;
    __shared__ float Jl[NJ][3];
    __shared__ float tm[NJ][16];
    __shared__ float ch[NJ][16];
    float R[9];

    if (t < NJ) {
        int j = t;
        float s[33];
#pragma unroll
        for (int i = 0; i < 33; i++) s[i] = 0.f;
        for (int c = 0; c < NCH; c++) {
            const float* pp = ws_jp + (size_t)(c * NJ + j) * 33;
#pragma unroll
            for (int i = 0; i < 33; i++) s[i] += pp[i];
        }
        float bb[NBETA];
#pragma unroll
        for (int l = 0; l < NBETA; l++) bb[l] = betas[b * NBETA + l];
#pragma unroll
        for (int k = 0; k < 3; k++) {
            float acc = s[k];
#pragma unroll
            for (int l = 0; l < NBETA; l++) acc += bb[l] * s[3 + k * NBETA + l];
            Jl[j][k] = acc;
        }
        // Rodrigues, matching reference: angle = ||aa + 1e-8||, rd = aa/angle
        float ax = pose[b * NJ * 3 + j * 3 + 0];
        float ay = pose[b * NJ * 3 + j * 3 + 1];
        float az = pose[b * NJ * 3 + j * 3 + 2];
        float e0 = ax + 1e-8f, e1 = ay + 1e-8f, e2 = az + 1e-8f;
        float ang = sqrtf(e0 * e0 + e1 * e1 + e2 * e2);
        float inv = 1.f / ang;
        float rx = ax * inv, ry = ay * inv, rz = az * inv;
        float sn = sinf(ang), cs = cosf(ang);
        float Km[9] = {0.f, -rz, ry, rz, 0.f, -rx, -ry, rx, 0.f};
#pragma unroll
        for (int r = 0; r < 3; r++)
#pragma unroll
            for (int c = 0; c < 3; c++) {
                float kk = Km[3 * r + 0] * Km[0 + c] + Km[3 * r + 1] * Km[3 + c] +
                           Km[3 * r + 2] * Km[6 + c];
                R[3 * r + c] = ((r == c) ? 1.f : 0.f) + sn * Km[3 * r + c] + (1.f - cs) * kk;
            }
        if (j >= 1) {
#pragma unroll
            for (int e = 0; e < 9; e++) {
                int r = e / 3, c = e % 3;
                ws_pf[b * NP + (j - 1) * 9 + e] = R[e] - ((r == c) ? 1.f : 0.f);
            }
        }
    }
    __syncthreads();
    if (t < NJ) {
        int j = t;
        int p = c_par[j];
        int ps = (p < 0) ? 0 : p;
#pragma unroll
        for (int r = 0; r < 3; r++) {
            tm[j][r * 4 + 0] = R[3 * r + 0];
            tm[j][r * 4 + 1] = R[3 * r + 1];
            tm[j][r * 4 + 2] = R[3 * r + 2];
            tm[j][r * 4 + 3] = (j == 0) ? Jl[j][r] : (Jl[j][r] - Jl[ps][r]);
        }
        tm[j][12] = 0.f; tm[j][13] = 0.f; tm[j][14] = 0.f; tm[j][15] = 1.f;
    }
    __syncthreads();
    if (t < 16) ch[0][t] = tm[0][t];
    __syncthreads();
    for (int i = 1; i < NJ; i++) {
        if (t < 16) {
            int r = t >> 2, c = t & 3;
            int p = c_par[i];
            ch[i][t] = ch[p][4 * r + 0] * tm[i][0 + c] + ch[p][4 * r + 1] * tm[i][4 + c] +
                       ch[p][4 * r + 2] * tm[i][8 + c] + ch[p][4 * r + 3] * tm[i][12 + c];
        }
        __syncthreads();
    }
    if (t < NJ) {
        int j = t;
        float ib[4];
#pragma unroll
        for (int p = 0; p < 4; p++)
            ib[p] = ch[j][4 * p + 0] * Jl[j][0] + ch[j][4 * p + 1] * Jl[j][1] +
                    ch[j][4 * p + 2] * Jl[j][2];
#pragma unroll
        for (int e = 0; e < 16; e++) {
            int r = e >> 2, c = e & 3;
            float tr = ch[j][e];
            float Ae = tr - ((c == 3) ? ib[r] : 0.f);
            out[OFF_TF + (size_t)(b * NJ + j) * 16 + e] = tr;
            out[OFF_A + (size_t)(b * NJ + j) * 16 + e] = Ae;
            ws_A[(size_t)(b * NJ + j) * 16 + e] = Ae;
        }
#pragma unroll
        for (int k = 0; k < 3; k++)
            out[OFF_PJ + (size_t)(b * NJ + j) * 3 + k] = ch[j][4 * k + 3];
    }
}

// ----------- K3 (FUSED): v_posed = vt + sd@betas + pf@posedirs ; verts = (lw@A)·vp
// r6/r8 lesson: NEVER pass an occupancy minimum to __launch_bounds__ — hipcc
// treats it as a hard VGPR cap and spills GBs to scratch (r8: VGPR=40, 3.9GB
// writes, 2.4ms). r7 lesson: VGPR=116 (fat epilogue live set) -> 4 waves/SIMD
// -> occupancy 17.6% -> latency-bound at 190us. This round: same structure,
// THIN epilogue so natural allocation lands <=64 VGPR (8 waves/SIMD; whole
// 1728-block grid co-resident):
//   - pass A: loop l=0..9 loading 3 sd scalars per step (L1-hot after l=0)
//     instead of preloading sdv[3][10] (30 live regs). Bit-identical order.
//   - pass B: lw 4-at-a-time, T[12] only.
// Broadcast operands (pf, A, betas) in LDS (r0-r5: s_load chains pin VALU 40%).
// XCD swizzle keeps each XCD's pd slice L2-resident (r2-verified: FETCH 7x down).
__global__ __launch_bounds__(256) void k_fused(
        const float* __restrict__ vt,
        const float* __restrict__ sd,
        const float* __restrict__ betas,
        const float* __restrict__ pd,
        const float* __restrict__ ws_pf,
        const float* __restrict__ ws_A,
        const float* __restrict__ lw,
        float* __restrict__ out) {
    int id = blockIdx.x;
    int xcd = id & 7, li = id >> 3;
    int nx = (xcd < 3) ? 4 : 3;                  // 27 x-slices = 3*4 + 5*3
    if (li >= nx * (BB / TBAT)) return;          // whole-block exit (before barriers)
    int x = xcd + 8 * (li % nx);
    int b0 = (li / nx) * TBAT;
    int t = threadIdx.x;
    int v = x * 256 + t;
    bool act = (v < VV);
    int vc = act ? v : (VV - 1);                 // clamp reads; predicate writes
    int n0 = vc * 3;

    __shared__ __align__(16) float pfs[TBAT][208];   // pose_feature rows (207 + pad)
    __shared__ __align__(16) float As[TBAT][288];    // A[:3][:4] rows, flat 24*12
    __shared__ __align__(16) float bbs[TBAT][NBETA];

    // ---- stage broadcast operands (coalesced, all threads participate)
    for (int idx = t; idx < TBAT * NP; idx += 256) {
        int bi = idx / NP, p = idx - bi * NP;
        pfs[bi][p] = ws_pf[(size_t)(b0 + bi) * NP + p];
    }
    for (int idx = t; idx < TBAT * 288; idx += 256) {
        int bi = idx / 288, r = idx - bi * 288;
        int j = r / 12, e = r - j * 12;
        As[bi][r] = ws_A[(size_t)(b0 + bi) * (NJ * 16) + j * 16 + e];
    }
    if (t < TBAT * NBETA) {
        int bi = t / NBETA, l = t - bi * NBETA;
        bbs[bi][l] = betas[(size_t)(b0 + bi) * NBETA + l];
    }
    __syncthreads();

    float acc0[TBAT], acc1[TBAT], acc2[TBAT];
#pragma unroll
    for (int bi = 0; bi < TBAT; bi++) { acc0[bi] = 0.f; acc1[bi] = 0.f; acc2[bi] = 0.f; }

    const float* __restrict__ pdp = pd + n0;

    // ---- main loop: 51 chunks of 4 rows (rows 0..203), then 3-row tail
#pragma unroll 1
    for (int c0 = 0; c0 < 204; c0 += 4) {
        float p0[4], p1[4], p2[4];
#pragma unroll
        for (int pc = 0; pc < 4; pc++) {
            const float* rp = pdp + (size_t)(c0 + pc) * N3;
            p0[pc] = rp[0]; p1[pc] = rp[1]; p2[pc] = rp[2];   // dwordx3/wave
        }
#pragma unroll
        for (int bi = 0; bi < TBAT; bi++) {
            float2 wa = *(const float2*)&pfs[bi][c0];         // b64 broadcast
            float2 wb = *(const float2*)&pfs[bi][c0 + 2];
            acc0[bi] += wa.x * p0[0]; acc1[bi] += wa.x * p1[0]; acc2[bi] += wa.x * p2[0];
            acc0[bi] += wa.y * p0[1]; acc1[bi] += wa.y * p1[1]; acc2[bi] += wa.y * p2[1];
            acc0[bi] += wb.x * p0[2]; acc1[bi] += wb.x * p1[2]; acc2[bi] += wb.x * p2[2];
            acc0[bi] += wb.y * p0[3]; acc1[bi] += wb.y * p1[3]; acc2[bi] += wb.y * p2[3];
        }
    }
    {   // tail: rows 204..206
        float p0[3], p1[3], p2[3];
#pragma unroll
        for (int pc = 0; pc < 3; pc++) {
            const float* rp = pdp + (size_t)(204 + pc) * N3;
            p0[pc] = rp[0]; p1[pc] = rp[1]; p2[pc] = rp[2];
        }
#pragma unroll
        for (int bi = 0; bi < TBAT; bi++) {
            float w0 = pfs[bi][204], w1 = pfs[bi][205], w2 = pfs[bi][206];
            acc0[bi] += w0 * p0[0]; acc1[bi] += w0 * p1[0]; acc2[bi] += w0 * p2[0];
            acc0[bi] += w1 * p0[1]; acc1[bi] += w1 * p1[1]; acc2[bi] += w1 * p2[1];
            acc0[bi] += w2 * p0[2]; acc1[bi] += w2 * p1[2]; acc2[bi] += w2 * p2[2];
        }
    }

    // ---- pass A (THIN): vp = vt + acc + sd@betas, accumulated in place.
    // Per-element order identical to r7: (vt + acc_pf) then l=0..9 ascending.
    {
        float vt0 = vt[n0], vt1 = vt[n0 + 1], vt2 = vt[n0 + 2];
#pragma unroll
        for (int bi = 0; bi < TBAT; bi++) {
            acc0[bi] += vt0; acc1[bi] += vt1; acc2[bi] += vt2;
        }
        const float* __restrict__ sdp = sd + (size_t)vc * 30;   // (3,10) row-major
#pragma unroll
        for (int l = 0; l < NBETA; l++) {
            float s0 = sdp[l], s1 = sdp[10 + l], s2 = sdp[20 + l];  // L1-hot after l=0
#pragma unroll
            for (int bi = 0; bi < TBAT; bi++) {
                float bl = bbs[bi][l];                   // b32 broadcast
                acc0[bi] += bl * s0;
                acc1[bi] += bl * s1;
                acc2[bi] += bl * s2;
            }
        }
        if (act) {
#pragma unroll
            for (int bi = 0; bi < TBAT; bi++) {
                float* op = &out[OFF_VP + (size_t)(b0 + bi) * N3 + n0];
                op[0] = acc0[bi]; op[1] = acc1[bi]; op[2] = acc2[bi];
            }
        }
    }
    __builtin_amdgcn_sched_barrier(0);   // keep pass B's As reads from hoisting into A

    // ---- pass B: T = lw@A (LDS b128 broadcast); verts from in-register vp.
#pragma unroll
    for (int bi = 0; bi < TBAT; bi++) {
        float T[12];
#pragma unroll
        for (int e = 0; e < 12; e++) T[e] = 0.f;
#pragma unroll
        for (int j0 = 0; j0 < NJ; j0 += 4) {
            const float4 w4 = *(const float4*)&lw[(size_t)vc * NJ + j0];  // L1-hot after bi=0
#pragma unroll
            for (int jj = 0; jj < 4; jj++) {
                int j = j0 + jj;
                float wj = (jj == 0) ? w4.x : (jj == 1) ? w4.y : (jj == 2) ? w4.z : w4.w;
                const float4 a0 = *(const float4*)&As[bi][j * 12 + 0];   // b128 broadcast
                const float4 a1 = *(const float4*)&As[bi][j * 12 + 4];
                const float4 a2 = *(const float4*)&As[bi][j * 12 + 8];
                T[0] += wj * a0.x; T[1] += wj * a0.y; T[2]  += wj * a0.z; T[3]  += wj * a0.w;
                T[4] += wj * a1.x; T[5] += wj * a1.y; T[6]  += wj * a1.z; T[7]  += wj * a1.w;
                T[8] += wj * a2.x; T[9] += wj * a2.y; T[10] += wj * a2.z; T[11] += wj * a2.w;
            }
        }
        if (act) {
            float s0 = acc0[bi], s1 = acc1[bi], s2 = acc2[bi];
            float* op = &out[OFF_VERTS + (size_t)(b0 + bi) * N3 + n0];
            op[0] = T[0] * s0 + T[1] * s1 + T[2]  * s2 + T[3];
            op[1] = T[4] * s0 + T[5] * s1 + T[6]  * s2 + T[7];
            op[2] = T[8] * s0 + T[9] * s1 + T[10] * s2 + T[11];
        }
    }
}

extern "C" void kernel_launch(void* const* d_in, const int* in_sizes, int n_in,
                              void* d_out, int out_size, void* d_ws, size_t ws_size,
                              hipStream_t stream) {
    const float* betas = (const float*)d_in[0];
    const float* pose  = (const float*)d_in[1];
    const float* vt    = (const float*)d_in[2];
    const float* sd    = (const float*)d_in[3];
    const float* pd    = (const float*)d_in[4];
    const float* jr    = (const float*)d_in[5];
    const float* lw    = (const float*)d_in[6];
    float* out = (float*)d_out;
    float* ws = (float*)d_ws;

    k_jreg<<<dim3(NJ, NCH), 256, 0, stream>>>(jr, vt, sd, ws + WS_JP);
    k_chain<<<BB, 64, 0, stream>>>(betas, pose, ws + WS_JP, ws + WS_PF,
                                   ws + WS_A, out);
    // 8 XCDs x max 4 x-slices x 64 batch-groups = 2048 launched, 1728 live
    k_fused<<<8 * 4 * (BB / TBAT), 256, 0, stream>>>(
        vt, sd, betas, pd, ws + WS_PF, ws + WS_A, lw, out);
}

// Round 10
// 311.496 us; speedup vs baseline: 7.7937x; 1.4182x over previous
//
#include <hip/hip_runtime.h>
#include <hip/hip_bf16.h>

#define BB 512
#define VV 6890
#define NJ 24
#define NBETA 10
#define NP 207          // (24-1)*9
#define N3 (VV*3)       // 20670
#define TBAT 8          // batch tile in k_fused
#define NCH 16          // v-chunks in k_jreg
#define CHV ((VV + NCH - 1) / NCH)   // 431

// d_out element offsets (fp32), concatenated in return order:
// verts (B,V,3), posed_joints (B,J,3), A (B,J,4,4), transforms (B,J,4,4), v_posed (B,V,3)
#define OFF_VERTS 0
#define OFF_PJ   (BB*VV*3)
#define OFF_A    (OFF_PJ + BB*NJ*3)
#define OFF_TF   (OFF_A + BB*NJ*16)
#define OFF_VP   (OFF_TF + BB*NJ*16)

// ws layout (fp32 elements)
#define WS_JP   0                        // NCH*24*33 partials of [JT[3]|JS[30]]
#define WS_PF   (WS_JP + NCH*NJ*33)      // B*207 pose_feature
#define WS_A    (WS_PF + BB*NP)          // B*24*16 fp32 A

// SMPL parents are a compile-time constant in the reference — hardcoded.
__constant__ int c_par[NJ] = {-1, 0, 0, 0, 1, 2, 3, 4, 5, 6, 7, 8,
                              9, 9, 9, 12, 13, 14, 16, 17, 18, 19, 20, 21};

// ------------------------------------------------- K1: partial JT/JS sums
__global__ __launch_bounds__(256) void k_jreg(const float* __restrict__ jr,
                                              const float* __restrict__ vt,
                                              const float* __restrict__ sd,
                                              float* __restrict__ ws_jp) {
    int j = blockIdx.x, ch = blockIdx.y;
    int t = threadIdx.x;
    int v0 = ch * CHV;
    int vend = (v0 + CHV < VV) ? (v0 + CHV) : VV;

    float acc[33];
#pragma unroll
    for (int i = 0; i < 33; i++) acc[i] = 0.f;

    for (int v = v0 + t; v < vend; v += 256) {
        float a = jr[(size_t)j * VV + v];
        acc[0] += a * vt[v * 3 + 0];
        acc[1] += a * vt[v * 3 + 1];
        acc[2] += a * vt[v * 3 + 2];
        const float2* sp = (const float2*)&sd[(size_t)v * 30];   // 8B-aligned
#pragma unroll
        for (int i = 0; i < 15; i++) {
            float2 s = sp[i];
            acc[3 + 2 * i] += a * s.x;
            acc[4 + 2 * i] += a * s.y;
        }
    }

    __shared__ float red[33][256];
#pragma unroll
    for (int i = 0; i < 33; i++) red[i][t] = acc[i];
    __syncthreads();
    for (int s = 128; s > 0; s >>= 1) {
        if (t < s) {
#pragma unroll
            for (int i = 0; i < 33; i++) red[i][t] += red[i][t + s];
        }
        __syncthreads();
    }
    if (t < 33) ws_jp[(size_t)(ch * NJ + j) * 33 + t] = red[t][0];
}

// ------------------------------- K2: Jloc, Rodrigues, chain, A/transforms/joints
__global__ __launch_bounds__(64) void k_chain(
        const float* __restrict__ betas,
        const float* __restrict__ pose,
        const float* __restrict__ ws_jp,
        float* __restrict__ ws_pf,
        float* __restrict__ ws_A,
        float* __restrict__ out) {
    int b = blockIdx.x;
    int t = threadIdx.x;
    __shared__ float Jl[NJ][3];
    __shared__ float tm[NJ][16];
    __shared__ float ch[NJ][16];
    float R[9];

    if (t < NJ) {
        int j = t;
        float s[33];
#pragma unroll
        for (int i = 0; i < 33; i++) s[i] = 0.f;
        for (int c = 0; c < NCH; c++) {
            const float* pp = ws_jp + (size_t)(c * NJ + j) * 33;
#pragma unroll
            for (int i = 0; i < 33; i++) s[i] += pp[i];
        }
        float bb[NBETA];
#pragma unroll
        for (int l = 0; l < NBETA; l++) bb[l] = betas[b * NBETA + l];
#pragma unroll
        for (int k = 0; k < 3; k++) {
            float acc = s[k];
#pragma unroll
            for (int l = 0; l < NBETA; l++) acc += bb[l] * s[3 + k * NBETA + l];
            Jl[j][k] = acc;
        }
        // Rodrigues, matching reference: angle = ||aa + 1e-8||, rd = aa/angle
        float ax = pose[b * NJ * 3 + j * 3 + 0];
        float ay = pose[b * NJ * 3 + j * 3 + 1];
        float az = pose[b * NJ * 3 + j * 3 + 2];
        float e0 = ax + 1e-8f, e1 = ay + 1e-8f, e2 = az + 1e-8f;
        float ang = sqrtf(e0 * e0 + e1 * e1 + e2 * e2);
        float inv = 1.f / ang;
        float rx = ax * inv, ry = ay * inv, rz = az * inv;
        float sn = sinf(ang), cs = cosf(ang);
        float Km[9] = {0.f, -rz, ry, rz, 0.f, -rx, -ry, rx, 0.f};
#pragma unroll
        for (int r = 0; r < 3; r++)
#pragma unroll
            for (int c = 0; c < 3; c++) {
                float kk = Km[3 * r + 0] * Km[0 + c] + Km[3 * r + 1] * Km[3 + c] +
                           Km[3 * r + 2] * Km[6 + c];
                R[3 * r + c] = ((r == c) ? 1.f : 0.f) + sn * Km[3 * r + c] + (1.f - cs) * kk;
            }
        if (j >= 1) {
#pragma unroll
            for (int e = 0; e < 9; e++) {
                int r = e / 3, c = e % 3;
                ws_pf[b * NP + (j - 1) * 9 + e] = R[e] - ((r == c) ? 1.f : 0.f);
            }
        }
    }
    __syncthreads();
    if (t < NJ) {
        int j = t;
        int p = c_par[j];
        int ps = (p < 0) ? 0 : p;
#pragma unroll
        for (int r = 0; r < 3; r++) {
            tm[j][r * 4 + 0] = R[3 * r + 0];
            tm[j][r * 4 + 1] = R[3 * r + 1];
            tm[j][r * 4 + 2] = R[3 * r + 2];
            tm[j][r * 4 + 3] = (j == 0) ? Jl[j][r] : (Jl[j][r] - Jl[ps][r]);
        }
        tm[j][12] = 0.f; tm[j][13] = 0.f; tm[j][14] = 0.f; tm[j][15] = 1.f;
    }
    __syncthreads();
    if (t < 16) ch[0][t] = tm[0][t];
    __syncthreads();
    for (int i = 1; i < NJ; i++) {
        if (t < 16) {
            int r = t >> 2, c = t & 3;
            int p = c_par[i];
            ch[i][t] = ch[p][4 * r + 0] * tm[i][0 + c] + ch[p][4 * r + 1] * tm[i][4 + c] +
                       ch[p][4 * r + 2] * tm[i][8 + c] + ch[p][4 * r + 3] * tm[i][12 + c];
        }
        __syncthreads();
    }
    if (t < NJ) {
        int j = t;
        float ib[4];
#pragma unroll
        for (int p = 0; p < 4; p++)
            ib[p] = ch[j][4 * p + 0] * Jl[j][0] + ch[j][4 * p + 1] * Jl[j][1] +
                    ch[j][4 * p + 2] * Jl[j][2];
#pragma unroll
        for (int e = 0; e < 16; e++) {
            int r = e >> 2, c = e & 3;
            float tr = ch[j][e];
            float Ae = tr - ((c == 3) ? ib[r] : 0.f);
            out[OFF_TF + (size_t)(b * NJ + j) * 16 + e] = tr;
            out[OFF_A + (size_t)(b * NJ + j) * 16 + e] = Ae;
            ws_A[(size_t)(b * NJ + j) * 16 + e] = Ae;
        }
#pragma unroll
        for (int k = 0; k < 3; k++)
            out[OFF_PJ + (size_t)(b * NJ + j) * 3 + k] = ch[j][4 * k + 3];
    }
}

// ----------- K3 (FUSED): v_posed = vt + sd@betas + pf@posedirs ; verts = (lw@A)·vp
// VGPR discipline, the lesson of r6-r9:
//   * never pass an occupancy arg to __launch_bounds__ (r6/r8: hard VGPR cap
//     -> GB-scale scratch spills).
//   * hipcc hoists every independent load to the top of a scheduling region and
//     interleaves fully-unrolled loops: r7/r9's unrolled pass B kept 8xT[12]
//     live (VGPR 116/164, occupancy 17%/10%). The reliable lever is
//     #pragma unroll 1 on the bi loop.
//   * occupancy halves at VGPR 64/128 -> target <=64 (8 waves/SIMD).
// Structure: main loop (acc24+p12 live ~50) -> thin pass A (unroll-1 l-loop,
// 3 loads/iter, stores vp) -> pass B unroll-1 over bi, re-reading vp from out
// as VOLATILE (blocks store-to-load forwarding so acc dies; same-thread L2-hot
// re-read is the r5-verified pattern). Broadcast operands (pf, A, betas) in LDS
// (r0-r5: s_load chains pin VALU at 40%). XCD swizzle keeps pd L2-resident.
__global__ __launch_bounds__(256) void k_fused(
        const float* __restrict__ vt,
        const float* __restrict__ sd,
        const float* __restrict__ betas,
        const float* __restrict__ pd,
        const float* __restrict__ ws_pf,
        const float* __restrict__ ws_A,
        const float* __restrict__ lw,
        float* __restrict__ out) {
    int id = blockIdx.x;
    int xcd = id & 7, li = id >> 3;
    int nx = (xcd < 3) ? 4 : 3;                  // 27 x-slices = 3*4 + 5*3
    if (li >= nx * (BB / TBAT)) return;          // whole-block exit (before barriers)
    int x = xcd + 8 * (li % nx);
    int b0 = (li / nx) * TBAT;
    int t = threadIdx.x;
    int v = x * 256 + t;
    bool act = (v < VV);
    int vc = act ? v : (VV - 1);                 // clamp reads; predicate writes
    int n0 = vc * 3;

    __shared__ __align__(16) float pfs[TBAT][208];   // pose_feature rows (207 + pad)
    __shared__ __align__(16) float As[TBAT][288];    // A[:3][:4] rows, flat 24*12
    __shared__ __align__(16) float bbs[TBAT][NBETA];

    // ---- stage broadcast operands (coalesced, all threads participate)
    for (int idx = t; idx < TBAT * NP; idx += 256) {
        int bi = idx / NP, p = idx - bi * NP;
        pfs[bi][p] = ws_pf[(size_t)(b0 + bi) * NP + p];
    }
    for (int idx = t; idx < TBAT * 288; idx += 256) {
        int bi = idx / 288, r = idx - bi * 288;
        int j = r / 12, e = r - j * 12;
        As[bi][r] = ws_A[(size_t)(b0 + bi) * (NJ * 16) + j * 16 + e];
    }
    if (t < TBAT * NBETA) {
        int bi = t / NBETA, l = t - bi * NBETA;
        bbs[bi][l] = betas[(size_t)(b0 + bi) * NBETA + l];
    }
    __syncthreads();

    float acc0[TBAT], acc1[TBAT], acc2[TBAT];
#pragma unroll
    for (int bi = 0; bi < TBAT; bi++) { acc0[bi] = 0.f; acc1[bi] = 0.f; acc2[bi] = 0.f; }

    const float* __restrict__ pdp = pd + n0;

    // ---- main loop: 51 chunks of 4 rows (rows 0..203), then 3-row tail
#pragma unroll 1
    for (int c0 = 0; c0 < 204; c0 += 4) {
        float p0[4], p1[4], p2[4];
#pragma unroll
        for (int pc = 0; pc < 4; pc++) {
            const float* rp = pdp + (size_t)(c0 + pc) * N3;
            p0[pc] = rp[0]; p1[pc] = rp[1]; p2[pc] = rp[2];   // dwordx3/wave
        }
#pragma unroll
        for (int bi = 0; bi < TBAT; bi++) {
            float2 wa = *(const float2*)&pfs[bi][c0];         // b64 broadcast
            float2 wb = *(const float2*)&pfs[bi][c0 + 2];
            acc0[bi] += wa.x * p0[0]; acc1[bi] += wa.x * p1[0]; acc2[bi] += wa.x * p2[0];
            acc0[bi] += wa.y * p0[1]; acc1[bi] += wa.y * p1[1]; acc2[bi] += wa.y * p2[1];
            acc0[bi] += wb.x * p0[2]; acc1[bi] += wb.x * p1[2]; acc2[bi] += wb.x * p2[2];
            acc0[bi] += wb.y * p0[3]; acc1[bi] += wb.y * p1[3]; acc2[bi] += wb.y * p2[3];
        }
    }
    {   // tail: rows 204..206
        float p0[3], p1[3], p2[3];
#pragma unroll
        for (int pc = 0; pc < 3; pc++) {
            const float* rp = pdp + (size_t)(204 + pc) * N3;
            p0[pc] = rp[0]; p1[pc] = rp[1]; p2[pc] = rp[2];
        }
#pragma unroll
        for (int bi = 0; bi < TBAT; bi++) {
            float w0 = pfs[bi][204], w1 = pfs[bi][205], w2 = pfs[bi][206];
            acc0[bi] += w0 * p0[0]; acc1[bi] += w0 * p1[0]; acc2[bi] += w0 * p2[0];
            acc0[bi] += w1 * p0[1]; acc1[bi] += w1 * p1[1]; acc2[bi] += w1 * p2[1];
            acc0[bi] += w2 * p0[2]; acc1[bi] += w2 * p1[2]; acc2[bi] += w2 * p2[2];
        }
    }

    // ---- pass A (thin, unroll-1 so the 30 sd loads are NOT hoisted together):
    // vp = (vt + acc_pf) then l=0..9 ascending — same per-element order as r7.
    {
        float vt0 = vt[n0], vt1 = vt[n0 + 1], vt2 = vt[n0 + 2];
#pragma unroll
        for (int bi = 0; bi < TBAT; bi++) {
            acc0[bi] += vt0; acc1[bi] += vt1; acc2[bi] += vt2;
        }
        const float* __restrict__ sdp = sd + (size_t)vc * 30;   // (3,10) row-major
#pragma unroll 1
        for (int l = 0; l < NBETA; l++) {
            float s0 = sdp[l], s1 = sdp[10 + l], s2 = sdp[20 + l];
#pragma unroll
            for (int bi = 0; bi < TBAT; bi++) {
                float bl = bbs[bi][l];                   // b32 broadcast
                acc0[bi] += bl * s0;
                acc1[bi] += bl * s1;
                acc2[bi] += bl * s2;
            }
        }
        if (act) {
#pragma unroll
            for (int bi = 0; bi < TBAT; bi++) {
                float* op = &out[OFF_VP + (size_t)(b0 + bi) * N3 + n0];
                op[0] = acc0[bi]; op[1] = acc1[bi]; op[2] = acc2[bi];
            }
        }
    }

    // ---- pass B (unroll-1 over bi: prevents 8xT[12] interleave that gave
    // VGPR 116/164 in r7/r9): T = lw@A from LDS; vp re-read VOLATILE from out
    // (same thread, just-written, L2-hot; volatile blocks store-forwarding so
    // acc registers die at the end of pass A).
    const volatile float* vp_rd = out + OFF_VP;
#pragma unroll 1
    for (int bi = 0; bi < TBAT; bi++) {
        float T[12];
#pragma unroll
        for (int e = 0; e < 12; e++) T[e] = 0.f;
#pragma unroll
        for (int j0 = 0; j0 < NJ; j0 += 4) {
            const float4 w4 = *(const float4*)&lw[(size_t)vc * NJ + j0];  // LICM-hoisted
#pragma unroll
            for (int jj = 0; jj < 4; jj++) {
                int j = j0 + jj;
                float wj = (jj == 0) ? w4.x : (jj == 1) ? w4.y : (jj == 2) ? w4.z : w4.w;
                const float4 a0 = *(const float4*)&As[bi][j * 12 + 0];   // b128 broadcast
                const float4 a1 = *(const float4*)&As[bi][j * 12 + 4];
                const float4 a2 = *(const float4*)&As[bi][j * 12 + 8];
                T[0] += wj * a0.x; T[1] += wj * a0.y; T[2]  += wj * a0.z; T[3]  += wj * a0.w;
                T[4] += wj * a1.x; T[5] += wj * a1.y; T[6]  += wj * a1.z; T[7]  += wj * a1.w;
                T[8] += wj * a2.x; T[9] += wj * a2.y; T[10] += wj * a2.z; T[11] += wj * a2.w;
            }
        }
        if (act) {
            size_t vb = (size_t)(b0 + bi) * N3 + n0;
            float s0 = vp_rd[vb + 0];
            float s1 = vp_rd[vb + 1];
            float s2 = vp_rd[vb + 2];
            float* op = &out[OFF_VERTS + vb];
            op[0] = T[0] * s0 + T[1] * s1 + T[2]  * s2 + T[3];
            op[1] = T[4] * s0 + T[5] * s1 + T[6]  * s2 + T[7];
            op[2] = T[8] * s0 + T[9] * s1 + T[10] * s2 + T[11];
        }
    }
}

extern "C" void kernel_launch(void* const* d_in, const int* in_sizes, int n_in,
                              void* d_out, int out_size, void* d_ws, size_t ws_size,
                              hipStream_t stream) {
    const float* betas = (const float*)d_in[0];
    const float* pose  = (const float*)d_in[1];
    const float* vt    = (const float*)d_in[2];
    const float* sd    = (const float*)d_in[3];
    const float* pd    = (const float*)d_in[4];
    const float* jr    = (const float*)d_in[5];
    const float* lw    = (const float*)d_in[6];
    float* out = (float*)d_out;
    float* ws = (float*)d_ws;

    k_jreg<<<dim3(NJ, NCH), 256, 0, stream>>>(jr, vt, sd, ws + WS_JP);
    k_chain<<<BB, 64, 0, stream>>>(betas, pose, ws + WS_JP, ws + WS_PF,
                                   ws + WS_A, out);
    // 8 XCDs x max 4 x-slices x 64 batch-groups = 2048 launched, 1728 live
    k_fused<<<8 * 4 * (BB / TBAT), 256, 0, stream>>>(
        vt, sd, betas, pd, ws + WS_PF, ws + WS_A, lw, out);
}